// Round 3
// baseline (468.850 us; speedup 1.0000x reference)
//
#include <hip/hip_runtime.h>
#include <hip/hip_fp16.h>
#include <math.h>

namespace {
constexpr int S = 192;
constexpr long long S2 = (long long)S * S;
constexpr long long S3 = (long long)S * S2;
constexpr int NB = 4;
constexpr int K = 11;
constexpr int R = 5;
constexpr int HCH = 32;   // A: h-outputs per block (6 chunks)
constexpr int DCH = 48;   // B: d-outputs per block (4 chunks)
constexpr float C1f = 1e-4f;
constexpr float C2f = 9e-4f;

struct GaussW { float g[K]; };

__global__ void k_final(const double* __restrict__ acc, float* __restrict__ out) {
  out[0] = (float)(acc[0] / (double)(NB * S3));
}

// ======================= Kernel A =======================
// Fused W+H blur. Fields 0..3 (mux,muy,bxx,byy) packed as 4xfp16 in uint2;
// field 4 (bxy) separate fp16.
// R9: BARRIER-FREE wave-private strips. R8's profile: VALUBusy=40% ==
// (VALU-serial work)/(wall time) exactly -> no stall was being covered by
// another wave: the 8 __syncthreads per block convoyed all waves into
// lockstep stage->barrier->consume phases. Now wave v owns output columns
// [64v,64v+64), stages its own 74-col halo rows into a private LDS buffer
// (20.1 KB/block, still 8 blocks/CU), and never synchronizes. Within-wave
// ds ordering is lgkmcnt-handled by the compiler; waves drift so one
// wave's stage hides under another's consume.

template <int NROWS, bool GUARD>
__device__ __forceinline__ void stageA(const float* pg, const float* pp, int r0,
                                       int l, int c1, bool c1ok, int c2, bool c2ok,
                                       float2 (*rb)[76]) {
  float a1[NROWS], b1[NROWS], a2[NROWS], b2[NROWS];  // transient
#pragma unroll
  for (int j = 0; j < NROWS; ++j) {
    int r = r0 + j;
    bool rok = !GUARD || ((unsigned)r < (unsigned)S);
    long long ro = (long long)r * S;
    a1[j] = (rok && c1ok) ? pg[ro + c1] : 0.f;
    b1[j] = (rok && c1ok) ? pp[ro + c1] : 0.f;
    a2[j] = (rok && c2ok) ? pg[ro + c2] : 0.f;
    b2[j] = (rok && c2ok) ? pp[ro + c2] : 0.f;
  }
#pragma unroll
  for (int j = 0; j < NROWS; ++j) {
    rb[j][l] = make_float2(a1[j], b1[j]);
    if (l < 10) rb[j][64 + l] = make_float2(a2[j], b2[j]);
  }
}

template <int NROWS, bool EMITALL>
__device__ __forceinline__ void consumeA(
    const float2 (*rb)[76], int l, const GaussW& Wt,
    float2 (&w01)[K], float2 (&w23)[K], float (&w4v)[K],
    uint2* p0123, __half* p4, long long obase, int hbase) {
#pragma unroll
  for (int j = 0; j < NROWS; ++j) {
    // W-blur the 5 products for staged row j; tap i reads strip col l+i
    float2 s01 = make_float2(0.f, 0.f), s23 = make_float2(0.f, 0.f);
    float s4 = 0.f;
#pragma unroll
    for (int i = 0; i < K; ++i) {
      float2 ab = rb[j][l + i];
      float g = Wt.g[i];
      s01.x = fmaf(g, ab.x, s01.x);
      s01.y = fmaf(g, ab.y, s01.y);
      float ta = g * ab.x, tb = g * ab.y;
      s23.x = fmaf(ta, ab.x, s23.x);
      s23.y = fmaf(tb, ab.y, s23.y);
      s4 = fmaf(ta, ab.y, s4);
    }
    w01[j] = s01; w23[j] = s23; w4v[j] = s4;  // ring slot = counter % 11 = j
    if (EMITALL || j == K - 1) {              // compile-time
      float2 m01 = make_float2(0.f, 0.f), m23 = make_float2(0.f, 0.f);
      float m4 = 0.f;
#pragma unroll
      for (int i = 0; i < K; ++i) {
        const int sl = (j + 1 + i) % K;       // compile-time
        float g = Wt.g[i];
        m01.x = fmaf(g, w01[sl].x, m01.x);
        m01.y = fmaf(g, w01[sl].y, m01.y);
        m23.x = fmaf(g, w23[sl].x, m23.x);
        m23.y = fmaf(g, w23[sl].y, m23.y);
        m4 = fmaf(g, w4v[sl], m4);
      }
      long long o = obase + (long long)(hbase + j) * S;
      __half2 h01 = __floats2half2_rn(m01.x, m01.y);
      __half2 h23 = __floats2half2_rn(m23.x, m23.y);
      uint2 v;
      v.x = __builtin_bit_cast(unsigned, h01);
      v.y = __builtin_bit_cast(unsigned, h23);
      p0123[o] = v;
      p4[o] = __float2half(m4);
    }
  }
}

// grid = (dz=S, hchunk=6, n); block = 192 (w). Batches of 11,11,11,9 rows.
// Row ranges: b0 = h0-5..h0+5 (GUARD: neg), b1 <= 176, b2 <= 187 (safe),
// b3 = h0+28..h0+36 <= 196 (GUARD). Zero barriers.
__global__ __launch_bounds__(192) void k_blurWH(
    const float* __restrict__ gt, const float* __restrict__ pr,
    uint2* __restrict__ p0123, __half* __restrict__ p4,
    long long in_base, GaussW Wt, double* __restrict__ acc, int zero_acc) {
  __shared__ float2 rowbuf[3][K][76];  // per-wave private strips
  const int w = threadIdx.x;
  const int l = w & 63;
  const int v = w >> 6;
  const int dz = blockIdx.x;
  const int h0 = (int)blockIdx.y * HCH;
  const long long n = blockIdx.z;

  // k_init folded in: A fully precedes any B on the stream.
  if (zero_acc && dz == 0 && blockIdx.y == 0 && n == 0 && w == 0) *acc = 0.0;

  const float* pg = gt + in_base + (n * S + dz) * S2;
  const float* pp = pr + in_base + (n * S + dz) * S2;
  const long long obase = (n * S + dz) * S2 + w;

  // strip columns: wave v needs input cols [64v-5, 64v+68]
  const int c1 = (v << 6) - 5 + l;           // lanes 0..63 -> rel cols -5..58
  const bool c1ok = (unsigned)c1 < (unsigned)S;
  const int c2 = (v << 6) + 59 + l;          // lanes 0..9  -> rel cols 59..68
  const bool c2ok = (l < 10) && (c2 < S);
  float2 (*rb)[76] = rowbuf[v];

  float2 w01[K], w23[K];
  float w4v[K];  // no init needed: batch0 writes all 11 slots before 1st emit

  stageA<K, true>(pg, pp, h0 - R, l, c1, c1ok, c2, c2ok, rb);
  consumeA<K, false>(rb, l, Wt, w01, w23, w4v, p0123, p4, obase, h0 - 10);
  stageA<K, false>(pg, pp, h0 + 6, l, c1, c1ok, c2, c2ok, rb);
  consumeA<K, true>(rb, l, Wt, w01, w23, w4v, p0123, p4, obase, h0 + 1);
  stageA<K, false>(pg, pp, h0 + 17, l, c1, c1ok, c2, c2ok, rb);
  consumeA<K, true>(rb, l, Wt, w01, w23, w4v, p0123, p4, obase, h0 + 12);
  stageA<9, true>(pg, pp, h0 + 28, l, c1, c1ok, c2, c2ok, rb);
  consumeA<9, true>(rb, l, Wt, w01, w23, w4v, p0123, p4, obase, h0 + 23);
}

// ======================= Kernel B =======================

template <int N, bool GUARD>
__device__ __forceinline__ void stageB(const uint2* q0123, const __half* q4,
                                       int plane0, uint2 (&sab)[K], __half (&se)[K]) {
#pragma unroll
  for (int j = 0; j < N; ++j) {
    int d = plane0 + j;
    bool ok = !GUARD || ((unsigned)d < (unsigned)S);
    long long o = (long long)d * S2;
    sab[j] = ok ? q0123[o] : make_uint2(0u, 0u);  // fp16 bits 0 == 0.0
    se[j] = ok ? q4[o] : __float2half(0.f);
  }
}

template <int NOUT>
__device__ __forceinline__ void consumeB(
    const uint2 (&sab)[K], const __half (&se)[K],
    const GaussW& Wt, float2 (&r01)[K], float2 (&r23)[K], float (&r4)[K],
    double& lsum) {
  float fsum = 0.f;
#pragma unroll
  for (int j = 0; j < NOUT; ++j) {
    const int sw = (10 + j) % K;              // compile-time commit slot
    r01[sw] = __half22float2(__builtin_bit_cast(__half2, sab[j].x));
    r23[sw] = __half22float2(__builtin_bit_cast(__half2, sab[j].y));
    r4[sw] = __half2float(se[j]);
    float2 m01 = make_float2(0.f, 0.f), m23 = make_float2(0.f, 0.f);
    float m4 = 0.f;
#pragma unroll
    for (int i = 0; i < K; ++i) {
      const int sl = (j + i) % K;             // compile-time
      float g = Wt.g[i];
      m01.x = fmaf(g, r01[sl].x, m01.x);
      m01.y = fmaf(g, r01[sl].y, m01.y);
      m23.x = fmaf(g, r23[sl].x, m23.x);
      m23.y = fmaf(g, r23[sl].y, m23.y);
      m4 = fmaf(g, r4[sl], m4);
    }
    float mux = m01.x, muy = m01.y, bxx = m23.x, byy = m23.y, bxy = m4;
    float mux2 = mux * mux, muy2 = muy * muy, muxy = mux * muy;
    float sx = bxx - mux2, sy = byy - muy2, sxy = bxy - muxy;
    float num = fmaf(2.f, muxy, C1f) * fmaf(2.f, sxy, C2f);
    float den = (mux2 + muy2 + C1f) * (sx + sy + C2f);
    fsum += 1.f - num * __builtin_amdgcn_rcpf(den);
  }
  lsum += (double)fsum;
}

// D-blur + SSIM + mean-reduce. grid = (h=S, n, dchunk=4); block = 192 (w).
// Register ring of 11 planes, ping-pong staging one 11-batch ahead.
__global__ __launch_bounds__(192) void k_blurD_ssim(
    const uint2* __restrict__ p0123, const __half* __restrict__ p4,
    double* __restrict__ acc, GaussW Wt) {
  const int w = threadIdx.x;
  const int h = blockIdx.x;
  const long long n = blockIdx.y;
  const int d0 = (int)blockIdx.z * DCH;
  const long long base = n * S3 + (long long)h * S + w;
  const uint2* q0123 = p0123 + base;
  const __half* q4 = p4 + base;

  float2 r01[K], r23[K];
  float r4[K];
  // preload counters 0..9 -> slots 0..9 (planes d0-5..d0+4, guard low)
#pragma unroll
  for (int c = 0; c < K - 1; ++c) {
    int d = d0 - R + c;
    if ((unsigned)d < (unsigned)S) {
      long long o = (long long)d * S2;
      uint2 v = q0123[o];
      r01[c] = __half22float2(__builtin_bit_cast(__half2, v.x));
      r23[c] = __half22float2(__builtin_bit_cast(__half2, v.y));
      r4[c] = __half2float(q4[o]);
    } else {
      r01[c] = make_float2(0.f, 0.f);
      r23[c] = make_float2(0.f, 0.f);
      r4[c] = 0.f;
    }
  }
  r01[K - 1] = make_float2(0.f, 0.f);
  r23[K - 1] = make_float2(0.f, 0.f);
  r4[K - 1] = 0.f;

  uint2 sab0[K], sab1[K];
  __half se0[K], se1[K];
  double lsum = 0.0;

  // plane ranges: d0+5..15, d0+16..26, d0+27..37 (max 181: safe);
  // d0+38..48 and d0+49..52 guarded (max 196).
  stageB<K, false>(q0123, q4, d0 + 5, sab0, se0);   // counters 10..20
  stageB<K, false>(q0123, q4, d0 + 16, sab1, se1);  // counters 21..31
  consumeB<K>(sab0, se0, Wt, r01, r23, r4, lsum);   // t = 0..10
  stageB<K, false>(q0123, q4, d0 + 27, sab0, se0);  // counters 32..42
  consumeB<K>(sab1, se1, Wt, r01, r23, r4, lsum);   // t = 11..21
  stageB<K, true>(q0123, q4, d0 + 38, sab1, se1);   // counters 43..53
  consumeB<K>(sab0, se0, Wt, r01, r23, r4, lsum);   // t = 22..32
  stageB<4, true>(q0123, q4, d0 + 49, sab0, se0);   // counters 54..57
  consumeB<K>(sab1, se1, Wt, r01, r23, r4, lsum);   // t = 33..43
  consumeB<4>(sab0, se0, Wt, r01, r23, r4, lsum);   // t = 44..47

  // block reduction: wave shuffle -> LDS -> one atomic per block
  double v = lsum;
#pragma unroll
  for (int o = 32; o > 0; o >>= 1) v += __shfl_down(v, o, 64);
  __shared__ double wsum[3];
  int lane = threadIdx.x & 63, wv = threadIdx.x >> 6;
  if (lane == 0) wsum[wv] = v;
  __syncthreads();
  if (threadIdx.x == 0) atomicAdd(acc, wsum[0] + wsum[1] + wsum[2]);
}

}  // namespace

extern "C" void kernel_launch(void* const* d_in, const int* in_sizes, int n_in,
                              void* d_out, int out_size, void* d_ws, size_t ws_size,
                              hipStream_t stream) {
  (void)in_sizes; (void)n_in; (void)out_size;
  const float* gt = (const float*)d_in[0];
  const float* pr = (const float*)d_in[1];
  float* out = (float*)d_out;
  double* acc = (double*)d_ws;

  GaussW W;
  {
    double gg[K], sum = 0.0;
    for (int i = 0; i < K; ++i) {
      double x = (double)(i - K / 2);
      gg[i] = exp(-(x * x) / (2.0 * 1.5 * 1.5)) / (sqrt(2.0 * M_PI) * 1.5);
      sum += gg[i];
    }
    for (int i = 0; i < K; ++i) W.g[i] = (float)(gg[i] / sum);
  }

  auto run = [&](long long base_n, int nb, int zero) {
    size_t vox = (size_t)nb * S3;
    uint2* p0123 = (uint2*)((char*)d_ws + 256);
    __half* p4 = (__half*)(p0123 + vox);
    k_blurWH<<<dim3(S, S / HCH, nb), dim3(192), 0, stream>>>(
        gt, pr, p0123, p4, base_n * S3, W, acc, zero);
    k_blurD_ssim<<<dim3(S, nb, S / DCH), dim3(192), 0, stream>>>(
        p0123, p4, acc, W);
  };
  auto need = [](int nb) { return (size_t)256 + (size_t)nb * S3 * 10; };  // 8+2 B/voxel

  // R8: nb=2 chunks keep the 141 MB per-chunk intermediate (plus 113 MB
  // inputs) mostly L3-resident; kept. R9: k_init folded into first A.
  if (ws_size >= need(2)) {
    run(0, 2, 1);
    run(2, 2, 0);
  } else {
    for (int g = 0; g < NB; ++g) run(g, 1, g == 0);
  }
  k_final<<<dim3(1), dim3(1), 0, stream>>>(acc, out);
}